// Round 9
// baseline (26.001 us; speedup 1.0000x reference)
//
#include <hip/hip_runtime.h>
#include <hip/hip_bf16.h>
#include <math.h>

#define BB 16
#define NN 2048
#define LOG2E 1.4426950408889634f
#define LN2   0.6931471805599453f

#define NCH 8                 // 256-chunks per row (sort/search)
#define NTILES 136            // triangular 16x16 grid of 128x128 tiles
#define TI 128
#define P_NBLK (NTILES * BB)  // 2176 pairwise blocks
#define S_NBLK (BB * NCH)     // 128 search blocks

// ws float offsets; everything written-before-read each call, no zero-init
#define OFF_TS   0                         // [128][256] sorted t (ascending)
#define OFF_EP   (128 * 256)               // [128][257] exclusive e-prefix
#define OFF_PPW  (OFF_EP + 128 * 257)      // [2176] weighted pair partials
#define OFF_LLP  (OFF_PPW + P_NBLK)        // [128] LL partials (log2 units)
#define OFF_TP   (OFF_LLP + S_NBLK)        // [128] T partials (log2 units)

// ---------- K0: per-256-chunk bitonic sort by t + exclusive prefix of e ----------
// chunk ch = b*8 + cn; global element = ch*256 + tid (NN = 8*256).
__global__ __launch_bounds__(256) void k0_sort(
    const float* __restrict__ pred, const float* __restrict__ tru,
    const float* __restrict__ masks, float* __restrict__ ws) {
  const int ch = blockIdx.x;
  const int tid = threadIdx.x;
  __shared__ float st[256], sp[256], sa[256], sb[256];

  const int g = ch * 256 + tid;
  float m = masks[g];
  st[tid] = tru[g] * m;
  sp[tid] = pred[g] * m * LOG2E;
  __syncthreads();

  // bitonic ascending sort of (t, P)
  for (int k = 2; k <= 256; k <<= 1) {
    for (int j = k >> 1; j > 0; j >>= 1) {
      int ixj = tid ^ j;
      if (ixj > tid) {
        bool up = ((tid & k) == 0);
        float a = st[tid], b2 = st[ixj];
        if (up ? (a > b2) : (a < b2)) {
          st[tid] = b2; st[ixj] = a;
          float pa = sp[tid]; sp[tid] = sp[ixj]; sp[ixj] = pa;
        }
      }
      __syncthreads();
    }
  }

  // e = 2^P (sorted order); Hillis-Steele inclusive scan
  float e = __builtin_amdgcn_exp2f(sp[tid]);
  sa[tid] = e;
  __syncthreads();
  float v = e;
  float* src = sa; float* dst = sb;
  for (int off = 1; off < 256; off <<= 1) {
    float add = (tid >= off) ? src[tid - off] : 0.f;
    v += add;
    dst[tid] = v;
    __syncthreads();
    float* t = src; src = dst; dst = t;
  }

  ws[OFF_TS + ch * 256 + tid] = st[tid];
  ws[OFF_EP + ch * 257 + tid] = v - e;                    // exclusive prefix
  if (tid == 255) ws[OFF_EP + ch * 257 + 256] = v;        // chunk total
}

// ---------- K1: dual role ----------
// bid < 128: search role. One row-chunk of 256 i's; for each i, 8 interleaved
//   branchless binary searches over the row's sorted chunks (LDS) give
//   lb = #{j in chunk : t_j < t_i}. E_i = e_i + sum epre[lb]; c_i = sum lb.
//   Outputs: LL = sum_i (P_i - log2 E_i), T = sum_i ((N-1) - 2 c_i) P_i.
// bid >= 128: pairwise role. Triangular 128x128 tile; per pair only
//   {d, |d| add, exp2(-|d|), fma into product}; one log2 per 64 pairs.
//   pp = 0.5*sum|d| + sum log2(1+2^-|d|); diag tiles weighted 0.5.
__global__ __launch_bounds__(256) void k1_main(
    const float* __restrict__ pred, const float* __restrict__ tru,
    const float* __restrict__ masks, float* __restrict__ ws) {
  __shared__ float shm[4112];   // search: lt[2048] + lep[2056]; pair: sPj[128]; red at 4104
  const int bid = blockIdx.x;
  const int tid = threadIdx.x;
  float* red = shm + 4104;

  if (bid < S_NBLK) {
    // ----- search role -----
    const int b = bid >> 3, sc = bid & 7;
    float* lt = shm;
    float* lep = shm + 2048;
    for (int k = tid; k < 2048; k += 256) lt[k] = ws[OFF_TS + b * 2048 + k];
    for (int k = tid; k < 2056; k += 256) lep[k] = ws[OFF_EP + b * 2056 + k];

    const int gi = b * NN + sc * 256 + tid;
    const float m = masks[gi];
    const float ti = tru[gi] * m;
    const float Pi = pred[gi] * m * LOG2E;
    __syncthreads();

    int lb[NCH] = {0, 0, 0, 0, 0, 0, 0, 0};
    #pragma unroll
    for (int s = 256; s >= 1; s >>= 1) {
      #pragma unroll
      for (int c = 0; c < NCH; ++c) {     // 8 independent ds_reads per step
        int mj = lb[c] + s;
        bool ok = (mj <= 256);
        int idx = ok ? (mj - 1) : 255;
        bool go = ok && (lt[c * 256 + idx] < ti);
        lb[c] = go ? mj : lb[c];
      }
    }
    float E = __builtin_amdgcn_exp2f(Pi);   // own term (j == i)
    int ci = 0;
    #pragma unroll
    for (int c = 0; c < NCH; ++c) {
      E += lep[c * 257 + lb[c]];
      ci += lb[c];
    }
    float LLi = Pi - __builtin_amdgcn_logf(E);             // log2(E)
    float Ti = ((float)(NN - 1) - 2.f * (float)ci) * Pi;

    #pragma unroll
    for (int off = 32; off >= 1; off >>= 1) {
      LLi += __shfl_down(LLi, off);
      Ti  += __shfl_down(Ti, off);
    }
    __syncthreads();
    if ((tid & 63) == 0) { red[tid >> 6] = LLi; red[4 + (tid >> 6)] = Ti; }
    __syncthreads();
    if (tid == 0) {
      ws[OFF_LLP + bid] = (red[0] + red[1]) + (red[2] + red[3]);
      ws[OFF_TP + bid]  = (red[4] + red[5]) + (red[6] + red[7]);
    }
  } else {
    // ----- pairwise role -----
    const int pb = bid - S_NBLK;
    const int b = pb / NTILES;
    int tt = pb - b * NTILES;
    int ic = 0, rem = tt, span = 16;
    while (rem >= span) { rem -= span; ++ic; --span; }
    const int jc = ic + rem;

    float* sPj = shm;
    if (tid < TI) {
      int gj = b * NN + jc * TI + tid;
      float mm = masks[gj];
      sPj[tid] = pred[gj] * mm * LOG2E;
    }
    const int il = tid & 127, jh = tid >> 7;
    const int gi = b * NN + ic * TI + il;
    const float mi = masks[gi];
    const float Pi = pred[gi] * mi * LOG2E;
    __syncthreads();

    float sAB0 = 0.f, sAB1 = 0.f, pr0 = 1.f, pr1 = 1.f;
    const float4* t4 = (const float4*)sPj + jh * 16;
    #pragma unroll
    for (int q = 0; q < 16; ++q) {
      float4 v = t4[q];                    // 1 broadcast b128 per 4 pairs
      float d0 = Pi - v.x;
      sAB0 += fabsf(d0);
      pr0 = __builtin_fmaf(__builtin_amdgcn_exp2f(-fabsf(d0)), pr0, pr0);
      float d1 = Pi - v.y;
      sAB1 += fabsf(d1);
      pr1 = __builtin_fmaf(__builtin_amdgcn_exp2f(-fabsf(d1)), pr1, pr1);
      float d2 = Pi - v.z;
      sAB0 += fabsf(d2);
      pr0 = __builtin_fmaf(__builtin_amdgcn_exp2f(-fabsf(d2)), pr0, pr0);
      float d3 = Pi - v.w;
      sAB1 += fabsf(d3);
      pr1 = __builtin_fmaf(__builtin_amdgcn_exp2f(-fabsf(d3)), pr1, pr1);
    }
    // 32 factors per product, each in (1,2] -> < 2^32: exact-safe in f32
    float pp = 0.5f * (sAB0 + sAB1) +
               __builtin_amdgcn_logf(pr0) + __builtin_amdgcn_logf(pr1);
    #pragma unroll
    for (int off = 32; off >= 1; off >>= 1) pp += __shfl_down(pp, off);
    __syncthreads();
    if ((tid & 63) == 0) red[tid >> 6] = pp;
    __syncthreads();
    if (tid == 0) {
      float w = (ic == jc) ? 0.5f : 1.0f;  // diag tiles double-visit
      ws[OFF_PPW + pb] = w * ((red[0] + red[1]) + (red[2] + red[3]));
    }
  }
}

// ---------- KC: combine ----------
__global__ __launch_bounds__(256) void kc_final(
    const float* __restrict__ ws, const float* __restrict__ lbl,
    float* __restrict__ out) {
  const int tid = threadIdx.x;
  __shared__ float red[12];

  float s = 0.f;
  for (int k = tid; k < P_NBLK; k += 256) s += ws[OFF_PPW + k];
  float l = 0.f, t = 0.f;
  if (tid < S_NBLK) { l = ws[OFF_LLP + tid]; t = ws[OFF_TP + tid]; }

  #pragma unroll
  for (int off = 32; off >= 1; off >>= 1) {
    s += __shfl_down(s, off);
    l += __shfl_down(l, off);
    t += __shfl_down(t, off);
  }
  const int w = tid >> 6, ln = tid & 63;
  if (ln == 0) { red[w] = s; red[4 + w] = l; red[8 + w] = t; }
  __syncthreads();
  if (tid == 0) {
    float S = (red[0] + red[1]) + (red[2] + red[3]);
    float L = (red[4] + red[5]) + (red[6] + red[7]);
    float T = (red[8] + red[9]) + (red[10] + red[11]);
    // PS(log2) = 0.5*(sum_u xd) + [0.5*sum_u|d| + sum_u log2(1+2^-|d|)]
    //            - 0.5*B*N   (self pairs contribute 1.0 at weight 0.5)
    float PS = 0.5f * T + S - 0.5f * (float)(BB * NN);
    float pairwise = LN2 * PS * 2.0f /
                     ((float)BB * (float)NN * (float)(NN - 1));
    float ranking = -LN2 * L / ((float)BB * (float)NN);
    out[0] = ranking + 0.3f * pairwise + 0.03f * lbl[0];
  }
}

extern "C" void kernel_launch(void* const* d_in, const int* in_sizes, int n_in,
                              void* d_out, int out_size, void* d_ws, size_t ws_size,
                              hipStream_t stream) {
  const float* y_pred = (const float*)d_in[0];
  const float* y_true = (const float*)d_in[1];
  const float* masks  = (const float*)d_in[2];
  const float* lbl    = (const float*)d_in[3];
  float* out = (float*)d_out;
  float* ws = (float*)d_ws;

  k0_sort<<<S_NBLK, 256, 0, stream>>>(y_pred, y_true, masks, ws);
  k1_main<<<S_NBLK + P_NBLK, 256, 0, stream>>>(y_pred, y_true, masks, ws);
  kc_final<<<1, 256, 0, stream>>>(ws, lbl, out);
}